// Round 6
// baseline (119.376 us; speedup 1.0000x reference)
//
#include <hip/hip_runtime.h>
#include <hip/hip_bf16.h>

#define BB 4
#define SS 256
#define DD 512
#define CC 128
#define NC 64
#define PXB 4    // pixels per block in pixel kernel
#define NTEXT 128  // text-role blocks (8 rows each)

// LDS overlays for the two proj roles
struct XRole { float xl[8][CC]; };                                    // 4 KB
struct TRole { float tel[8][DD];              // 16 KB
               float part[2][2][8][NC];       // 8 KB
               float ksl[8][NC]; float vsl[8][NC]; };                 // 4 KB
union ProjSH { XRole xr; TRole tr; };

// ---------------------------------------------------------------------------
// Kernel 1 (fused proj): blocks 0..127 = text role (8 rows, atomic M/Ks/Vs),
//                        blocks 128..639 = xproj role (8 px/block -> P).
// ---------------------------------------------------------------------------
__global__ __launch_bounds__(256) void proj_kernel(
    const float* __restrict__ x,
    const float* __restrict__ Wq,  const float* __restrict__ bq,
    const float* __restrict__ Wkx, const float* __restrict__ bkx,
    const float* __restrict__ Wvx, const float* __restrict__ bvx,
    const float* __restrict__ s,   const float* __restrict__ a,
    const float* __restrict__ Wks, const float* __restrict__ bks,
    const float* __restrict__ Wvs, const float* __restrict__ bvs,
    float* __restrict__ P, float* __restrict__ Mw,
    float* __restrict__ Ksw, float* __restrict__ Vsw)
{
    __shared__ ProjSH sh;
    const int t = threadIdx.x;
    const int w = t >> 6, lane = t & 63;
    const int blk = blockIdx.x;

    if (blk < NTEXT) {
        // ---------------- text role: 8 rows ----------------
        const int row0 = blk * 8;
        const int b = row0 >> 8;             // 256 rows per batch
        {
            const float4* s4 = (const float4*)(s + (size_t)row0 * DD);
            #pragma unroll
            for (int j = 0; j < 4; ++j) {
                const int i = t + j * 256;   // 1024 float4 = 8*512 floats
                const int r = i >> 7;
                const float am = a[row0 + r];
                float4 v = s4[i];
                v.x *= am; v.y *= am; v.z *= am; v.w *= am;
                ((float4*)&sh.tr.tel[0][0])[i] = v;
            }
        }
        __syncthreads();

        const int m = w & 1, h = w >> 1;
        const int kb = h * 256;
        const int cg4 = (lane & 15) * 4;
        const int ksub = lane >> 4;
        const float* __restrict__ Wm = m ? Wvs : Wks;

        float4 acc[8] = {};
        #pragma unroll 2
        for (int j = 0; j < 64; ++j) {
            const int k = kb + 4 * j + ksub;
            const float4 wv = *(const float4*)(Wm + (size_t)k * NC + cg4);
            #pragma unroll
            for (int r = 0; r < 8; ++r) {
                const float tv = sh.tr.tel[r][k];
                acc[r].x = fmaf(tv, wv.x, acc[r].x);
                acc[r].y = fmaf(tv, wv.y, acc[r].y);
                acc[r].z = fmaf(tv, wv.z, acc[r].z);
                acc[r].w = fmaf(tv, wv.w, acc[r].w);
            }
        }
        #pragma unroll
        for (int r = 0; r < 8; ++r) {
            #pragma unroll
            for (int off = 16; off <= 32; off <<= 1) {
                acc[r].x += __shfl_down(acc[r].x, off);
                acc[r].y += __shfl_down(acc[r].y, off);
                acc[r].z += __shfl_down(acc[r].z, off);
                acc[r].w += __shfl_down(acc[r].w, off);
            }
        }
        if (lane < 16) {
            #pragma unroll
            for (int r = 0; r < 8; ++r)
                *(float4*)&sh.tr.part[m][h][r][cg4] = acc[r];
        }
        __syncthreads();

        // combine k-halves + bias -> ksl/vsl (2 mats x 8 rows x 64 cols)
        #pragma unroll
        for (int i = t; i < 1024; i += 256) {
            const int mm = i >> 9;
            const int r = (i >> 6) & 7;
            const int col = i & 63;
            const float v = sh.tr.part[mm][0][r][col] + sh.tr.part[mm][1][r][col]
                          + (mm ? bvs[col] : bks[col]);
            if (mm) sh.tr.vsl[r][col] = v; else sh.tr.ksl[r][col] = v;
        }
        __syncthreads();

        // Ks / Vs partial sums (waves 0 and 1)
        if (w == 0) {
            float sk = 0.f;
            #pragma unroll
            for (int r = 0; r < 8; ++r) sk += sh.tr.ksl[r][lane];
            atomicAdd(&Ksw[b * NC + lane], sk);
        } else if (w == 1) {
            float sv = 0.f;
            #pragma unroll
            for (int r = 0; r < 8; ++r) sv += sh.tr.vsl[r][lane];
            atomicAdd(&Vsw[b * NC + lane], sv);
        }

        // M partial: rank-8 outer product, one atomic per (c,d) per block
        float* __restrict__ Mb = Mw + (size_t)b * NC * NC;
        #pragma unroll 4
        for (int j = 0; j < 16; ++j) {
            const int idx = t + j * 256;
            const int c = idx >> 6;          // wave-uniform
            float pm = 0.f;
            #pragma unroll
            for (int r = 0; r < 8; ++r)
                pm = fmaf(sh.tr.vsl[r][c], sh.tr.ksl[r][lane], pm);
            atomicAdd(Mb + idx, pm);
        }
    } else {
        // ---------------- xproj role: 8 pixels ----------------
        const int px0 = (blk - NTEXT) * 8;
        ((float4*)&sh.xr.xl[0][0])[t] =
            ((const float4*)(x + (size_t)px0 * CC))[t];   // 256 f4 = 8*128 f
        __syncthreads();
        if (w < 3) {
            const float* __restrict__ Wm = (w == 0) ? Wq : (w == 1 ? Wkx : Wvx);
            const float* __restrict__ bm = (w == 0) ? bq : (w == 1 ? bkx : bvx);
            const int ksub = lane >> 4;
            const int cg4 = (lane & 15) * 4;
            float4 acc[8] = {};
            #pragma unroll 4
            for (int j = 0; j < 32; ++j) {
                const int k = 4 * j + ksub;
                const float4 wv = *(const float4*)(Wm + (size_t)k * NC + cg4);
                #pragma unroll
                for (int px = 0; px < 8; ++px) {
                    const float xv = sh.xr.xl[px][k];
                    acc[px].x = fmaf(xv, wv.x, acc[px].x);
                    acc[px].y = fmaf(xv, wv.y, acc[px].y);
                    acc[px].z = fmaf(xv, wv.z, acc[px].z);
                    acc[px].w = fmaf(xv, wv.w, acc[px].w);
                }
            }
            #pragma unroll
            for (int px = 0; px < 8; ++px) {
                #pragma unroll
                for (int off = 16; off <= 32; off <<= 1) {
                    acc[px].x += __shfl_down(acc[px].x, off);
                    acc[px].y += __shfl_down(acc[px].y, off);
                    acc[px].z += __shfl_down(acc[px].z, off);
                    acc[px].w += __shfl_down(acc[px].w, off);
                }
            }
            if (ksub == 0) {
                const float4 bb = *(const float4*)(bm + cg4);
                #pragma unroll
                for (int px = 0; px < 8; ++px) {
                    float4 v;
                    v.x = acc[px].x + bb.x; v.y = acc[px].y + bb.y;
                    v.z = acc[px].z + bb.z; v.w = acc[px].w + bb.w;
                    *(float4*)(P + (size_t)(px0 + px) * 192 + w * 64 + cg4) = v;
                }
            }
        }
    }
}

// ---------------------------------------------------------------------------
// Kernel 2: per-pixel attention + out proj + residual + LN (unchanged R4).
// 1024 blocks x 256 thr, 4 pixels/block.
// A[c,d] = ((256*vx[c]+Vs[c])*kx[d] + vx[c]*Ks[d] + M[c,d]) / 8
// ---------------------------------------------------------------------------
__global__ __launch_bounds__(256) void pixel_kernel(
    const float* __restrict__ x, const float* __restrict__ P,
    const float* __restrict__ Wout, const float* __restrict__ bout,
    const float* __restrict__ ln_scale, const float* __restrict__ ln_bias,
    const float* __restrict__ Mw, const float* __restrict__ Ksw,
    const float* __restrict__ Vsw,
    float* __restrict__ out)
{
    __shared__ float Ml[NC * 65];
    __shared__ float projl[PXB][192];
    __shared__ float xl[PXB][CC];
    __shared__ float rsl[PXB][NC];
    __shared__ float mxl[PXB][NC];
    __shared__ float outl[PXB][NC];
    __shared__ float Ksl[NC], Vsl[NC];
    __shared__ float redl[2][2][4];

    const int t = threadIdx.x;
    const int w = t >> 6, lane = t & 63;
    const int px0g = blockIdx.x * PXB;
    const int b = px0g >> 10;

    {
        const float4* P4 = (const float4*)(P + (size_t)px0g * 192);
        for (int i = t; i < PXB * 192 / 4; i += 256)
            ((float4*)&projl[0][0])[i] = P4[i];
        const float4* x4 = (const float4*)(x + (size_t)px0g * CC);
        for (int i = t; i < PXB * CC / 4; i += 256)
            ((float4*)&xl[0][0])[i] = x4[i];
        const float* Mb = Mw + (size_t)b * NC * NC;
        for (int i = t; i < NC * NC; i += 256)
            Ml[(i >> 6) * 65 + (i & 63)] = Mb[i];
        if (t < NC) { Ksl[t] = Ksw[b * NC + t]; Vsl[t] = Vsw[b * NC + t]; }
    }
    __syncthreads();

    // pass 1: wave = pixel, lane = row c
    {
        const int px = w, c = lane;
        const float vxc = projl[px][128 + c];
        const float qc  = projl[px][c];
        const float uc  = fmaf(256.0f, vxc, Vsl[c]);
        float mx = -3.4e38f;
        #pragma unroll
        for (int d = 0; d < NC; ++d) {
            const float A = fmaf(uc, projl[px][64 + d],
                                 fmaf(vxc, Ksl[d], Ml[c * 65 + d])) * 0.125f;
            mx = fmaxf(mx, A);
        }
        float sum = 0.f;
        #pragma unroll
        for (int d = 0; d < NC; ++d) {
            const float A = fmaf(uc, projl[px][64 + d],
                                 fmaf(vxc, Ksl[d], Ml[c * 65 + d])) * 0.125f;
            sum += __expf(A - mx);
        }
        rsl[px][c] = qc / sum;
        mxl[px][c] = mx;
    }
    __syncthreads();

    // pass 2: wave = pixel, lane = col d
    {
        const int px = w, d = lane;
        const float kxd = projl[px][64 + d];
        const float Ksd = Ksl[d];
        float acc = 0.f;
        #pragma unroll 4
        for (int c = 0; c < NC; ++c) {
            const float vxc = projl[px][128 + c];
            const float uc = fmaf(256.0f, vxc, Vsl[c]);
            const float A = fmaf(uc, kxd, fmaf(vxc, Ksd, Ml[c * 65 + d])) * 0.125f;
            acc = fmaf(rsl[px][c], __expf(A - mxl[px][c]), acc);
        }
        outl[px][d] = acc;
    }
    __syncthreads();

    // out proj + residual + layernorm
    {
        const int col = t & 127;
        const int pxg = t >> 7;
        const int px0 = 2 * pxg, px1 = px0 + 1;
        float acc0 = 0.f, acc1 = 0.f;
        #pragma unroll 4
        for (int k = 0; k < NC; ++k) {
            const float wv = Wout[k * CC + col];
            acc0 = fmaf(outl[px0][k], wv, acc0);
            acc1 = fmaf(outl[px1][k], wv, acc1);
        }
        const float bb = bout[col];
        const float y0 = acc0 + bb + xl[px0][col];
        const float y1 = acc1 + bb + xl[px1][col];

        float s10 = y0, s20 = y0 * y0, s11 = y1, s21 = y1 * y1;
        #pragma unroll
        for (int off = 32; off >= 1; off >>= 1) {
            s10 += __shfl_down(s10, off);
            s20 += __shfl_down(s20, off);
            s11 += __shfl_down(s11, off);
            s21 += __shfl_down(s21, off);
        }
        const int half = (t >> 6) & 1;
        if (lane == 0) {
            redl[pxg][half][0] = s10; redl[pxg][half][1] = s20;
            redl[pxg][half][2] = s11; redl[pxg][half][3] = s21;
        }
        __syncthreads();
        const float S10 = redl[pxg][0][0] + redl[pxg][1][0];
        const float S20 = redl[pxg][0][1] + redl[pxg][1][1];
        const float S11 = redl[pxg][0][2] + redl[pxg][1][2];
        const float S21 = redl[pxg][0][3] + redl[pxg][1][3];
        const float mu0 = S10 * (1.f / 128.f);
        const float var0 = S20 * (1.f / 128.f) - mu0 * mu0;
        const float mu1 = S11 * (1.f / 128.f);
        const float var1 = S21 * (1.f / 128.f) - mu1 * mu1;
        const float r0 = rsqrtf(var0 + 1e-6f), r1 = rsqrtf(var1 + 1e-6f);
        const float gg = ln_scale[col], be = ln_bias[col];
        out[(size_t)(px0g + px0) * CC + col] = (y0 - mu0) * r0 * gg + be;
        out[(size_t)(px0g + px1) * CC + col] = (y1 - mu1) * r1 * gg + be;
    }
}

// ---------------------------------------------------------------------------
extern "C" void kernel_launch(void* const* d_in, const int* in_sizes, int n_in,
                              void* d_out, int out_size, void* d_ws, size_t ws_size,
                              hipStream_t stream) {
    const float* x        = (const float*)d_in[0];
    const float* s        = (const float*)d_in[1];
    const float* a        = (const float*)d_in[2];
    const float* Wq       = (const float*)d_in[3];
    const float* bq       = (const float*)d_in[4];
    const float* Wkx      = (const float*)d_in[5];
    const float* bkx      = (const float*)d_in[6];
    const float* Wvx      = (const float*)d_in[7];
    const float* bvx      = (const float*)d_in[8];
    const float* Wks      = (const float*)d_in[9];
    const float* bks      = (const float*)d_in[10];
    const float* Wvs      = (const float*)d_in[11];
    const float* bvs      = (const float*)d_in[12];
    const float* Wout     = (const float*)d_in[13];
    const float* bout     = (const float*)d_in[14];
    const float* ln_scale = (const float*)d_in[15];
    const float* ln_bias  = (const float*)d_in[16];

    float* ws  = (float*)d_ws;
    float* Mw  = ws;                 // 16384 floats
    float* Ksw = ws + 16384;         // 256
    float* Vsw = ws + 16640;         // 256
    float* Pw  = ws + 16896;         // 4096*192 = 786432

    // zero the atomic accumulators (Mw|Ksw|Vsw are contiguous: 16896 floats)
    hipMemsetAsync(Mw, 0, 16896 * sizeof(float), stream);

    proj_kernel<<<NTEXT + 512, 256, 0, stream>>>(
        x, Wq, bq, Wkx, bkx, Wvx, bvx, s, a, Wks, bks, Wvs, bvs,
        Pw, Mw, Ksw, Vsw);
    pixel_kernel<<<(BB * 1024) / PXB, 256, 0, stream>>>(
        x, Pw, Wout, bout, ln_scale, ln_bias, Mw, Ksw, Vsw, (float*)d_out);
}

// Round 7
// 118.448 us; speedup vs baseline: 1.0078x; 1.0078x over previous
//
#include <hip/hip_runtime.h>
#include <hip/hip_bf16.h>

#define BB 4
#define SS 256
#define DD 512
#define CC 128
#define NC 64
#define PXB 4    // pixels per block in pixel kernel
#define NTEXT 128  // text-role blocks (8 rows each)

// LDS overlays for the two proj roles
struct XRole { float xl[8][CC]; };                                    // 4 KB
struct TRole { float tel[8][DD];              // 16 KB
               float part[2][2][8][NC];       // 8 KB
               float ksl[8][NC]; float vsl[8][NC]; };                 // 4 KB
union ProjSH { XRole xr; TRole tr; };

// ---------------------------------------------------------------------------
// Kernel 1 (fused proj): blocks 0..127 = text role (8 rows, atomic M/Ks/Vs),
//                        blocks 128..639 = xproj role (8 px/block -> P).
// ---------------------------------------------------------------------------
__global__ __launch_bounds__(256) void proj_kernel(
    const float* __restrict__ x,
    const float* __restrict__ Wq,  const float* __restrict__ bq,
    const float* __restrict__ Wkx, const float* __restrict__ bkx,
    const float* __restrict__ Wvx, const float* __restrict__ bvx,
    const float* __restrict__ s,   const float* __restrict__ a,
    const float* __restrict__ Wks, const float* __restrict__ bks,
    const float* __restrict__ Wvs, const float* __restrict__ bvs,
    float* __restrict__ P, float* __restrict__ Mw,
    float* __restrict__ Ksw, float* __restrict__ Vsw)
{
    __shared__ ProjSH sh;
    const int t = threadIdx.x;
    const int w = t >> 6, lane = t & 63;
    const int blk = blockIdx.x;

    if (blk < NTEXT) {
        // ---------------- text role: 8 rows ----------------
        const int row0 = blk * 8;
        const int b = row0 >> 8;             // 256 rows per batch
        {
            const float4* s4 = (const float4*)(s + (size_t)row0 * DD);
            #pragma unroll
            for (int j = 0; j < 4; ++j) {
                const int i = t + j * 256;   // 1024 float4 = 8*512 floats
                const int r = i >> 7;
                const float am = a[row0 + r];
                float4 v = s4[i];
                v.x *= am; v.y *= am; v.z *= am; v.w *= am;
                ((float4*)&sh.tr.tel[0][0])[i] = v;
            }
        }
        __syncthreads();

        const int m = w & 1, h = w >> 1;
        const int kb = h * 256;
        const int cg4 = (lane & 15) * 4;
        const int ksub = lane >> 4;
        const float* __restrict__ Wm = m ? Wvs : Wks;

        float4 acc[8] = {};
        #pragma unroll 2
        for (int j = 0; j < 64; ++j) {
            const int k = kb + 4 * j + ksub;
            const float4 wv = *(const float4*)(Wm + (size_t)k * NC + cg4);
            #pragma unroll
            for (int r = 0; r < 8; ++r) {
                const float tv = sh.tr.tel[r][k];
                acc[r].x = fmaf(tv, wv.x, acc[r].x);
                acc[r].y = fmaf(tv, wv.y, acc[r].y);
                acc[r].z = fmaf(tv, wv.z, acc[r].z);
                acc[r].w = fmaf(tv, wv.w, acc[r].w);
            }
        }
        #pragma unroll
        for (int r = 0; r < 8; ++r) {
            #pragma unroll
            for (int off = 16; off <= 32; off <<= 1) {
                acc[r].x += __shfl_down(acc[r].x, off);
                acc[r].y += __shfl_down(acc[r].y, off);
                acc[r].z += __shfl_down(acc[r].z, off);
                acc[r].w += __shfl_down(acc[r].w, off);
            }
        }
        if (lane < 16) {
            #pragma unroll
            for (int r = 0; r < 8; ++r)
                *(float4*)&sh.tr.part[m][h][r][cg4] = acc[r];
        }
        __syncthreads();

        // combine k-halves + bias -> ksl/vsl (2 mats x 8 rows x 64 cols)
        #pragma unroll
        for (int i = t; i < 1024; i += 256) {
            const int mm = i >> 9;
            const int r = (i >> 6) & 7;
            const int col = i & 63;
            const float v = sh.tr.part[mm][0][r][col] + sh.tr.part[mm][1][r][col]
                          + (mm ? bvs[col] : bks[col]);
            if (mm) sh.tr.vsl[r][col] = v; else sh.tr.ksl[r][col] = v;
        }
        __syncthreads();

        // Ks / Vs partial sums (waves 0 and 1)
        if (w == 0) {
            float sk = 0.f;
            #pragma unroll
            for (int r = 0; r < 8; ++r) sk += sh.tr.ksl[r][lane];
            atomicAdd(&Ksw[b * NC + lane], sk);
        } else if (w == 1) {
            float sv = 0.f;
            #pragma unroll
            for (int r = 0; r < 8; ++r) sv += sh.tr.vsl[r][lane];
            atomicAdd(&Vsw[b * NC + lane], sv);
        }

        // M partial: rank-8 outer product, one atomic per (c,d) per block
        float* __restrict__ Mb = Mw + (size_t)b * NC * NC;
        #pragma unroll 4
        for (int j = 0; j < 16; ++j) {
            const int idx = t + j * 256;
            const int c = idx >> 6;          // wave-uniform
            float pm = 0.f;
            #pragma unroll
            for (int r = 0; r < 8; ++r)
                pm = fmaf(sh.tr.vsl[r][c], sh.tr.ksl[r][lane], pm);
            atomicAdd(Mb + idx, pm);
        }
    } else {
        // ---------------- xproj role: 8 pixels ----------------
        const int px0 = (blk - NTEXT) * 8;
        ((float4*)&sh.xr.xl[0][0])[t] =
            ((const float4*)(x + (size_t)px0 * CC))[t];   // 256 f4 = 8*128 f
        __syncthreads();
        if (w < 3) {
            const float* __restrict__ Wm = (w == 0) ? Wq : (w == 1 ? Wkx : Wvx);
            const float* __restrict__ bm = (w == 0) ? bq : (w == 1 ? bkx : bvx);
            const int ksub = lane >> 4;
            const int cg4 = (lane & 15) * 4;
            float4 acc[8] = {};
            #pragma unroll 4
            for (int j = 0; j < 32; ++j) {
                const int k = 4 * j + ksub;
                const float4 wv = *(const float4*)(Wm + (size_t)k * NC + cg4);
                #pragma unroll
                for (int px = 0; px < 8; ++px) {
                    const float xv = sh.xr.xl[px][k];
                    acc[px].x = fmaf(xv, wv.x, acc[px].x);
                    acc[px].y = fmaf(xv, wv.y, acc[px].y);
                    acc[px].z = fmaf(xv, wv.z, acc[px].z);
                    acc[px].w = fmaf(xv, wv.w, acc[px].w);
                }
            }
            #pragma unroll
            for (int px = 0; px < 8; ++px) {
                #pragma unroll
                for (int off = 16; off <= 32; off <<= 1) {
                    acc[px].x += __shfl_down(acc[px].x, off);
                    acc[px].y += __shfl_down(acc[px].y, off);
                    acc[px].z += __shfl_down(acc[px].z, off);
                    acc[px].w += __shfl_down(acc[px].w, off);
                }
            }
            if (ksub == 0) {
                const float4 bb = *(const float4*)(bm + cg4);
                #pragma unroll
                for (int px = 0; px < 8; ++px) {
                    float4 v;
                    v.x = acc[px].x + bb.x; v.y = acc[px].y + bb.y;
                    v.z = acc[px].z + bb.z; v.w = acc[px].w + bb.w;
                    *(float4*)(P + (size_t)(px0 + px) * 192 + w * 64 + cg4) = v;
                }
            }
        }
    }
}

// ---------------------------------------------------------------------------
// Kernel 2: per-pixel attention + out proj + residual + LN.
// 1024 blocks x 256 thr, 4 pixels/block. Pass 1 caches the 64 A-values in
// VGPRs (R1-measured 88 VGPR for this pattern -> fits the 128 cap of (256,4)).
// A[c,d] = ((256*vx[c]+Vs[c])*kx[d] + vx[c]*Ks[d] + M[c,d]) / 8
// ---------------------------------------------------------------------------
__global__ __launch_bounds__(256, 4) void pixel_kernel(
    const float* __restrict__ x, const float* __restrict__ P,
    const float* __restrict__ Wout, const float* __restrict__ bout,
    const float* __restrict__ ln_scale, const float* __restrict__ ln_bias,
    const float* __restrict__ Mw, const float* __restrict__ Ksw,
    const float* __restrict__ Vsw,
    float* __restrict__ out)
{
    __shared__ float Ml[NC * 65];
    __shared__ float projl[PXB][192];
    __shared__ float xl[PXB][CC];
    __shared__ float rsl[PXB][NC];
    __shared__ float mxl[PXB][NC];
    __shared__ float outl[PXB][NC];
    __shared__ float Ksl[NC], Vsl[NC];
    __shared__ float redl[2][2][4];

    const int t = threadIdx.x;
    const int w = t >> 6, lane = t & 63;
    const int px0g = blockIdx.x * PXB;
    const int b = px0g >> 10;

    {
        const float4* P4 = (const float4*)(P + (size_t)px0g * 192);
        for (int i = t; i < PXB * 192 / 4; i += 256)
            ((float4*)&projl[0][0])[i] = P4[i];
        const float4* x4 = (const float4*)(x + (size_t)px0g * CC);
        for (int i = t; i < PXB * CC / 4; i += 256)
            ((float4*)&xl[0][0])[i] = x4[i];
        const float* Mb = Mw + (size_t)b * NC * NC;
        for (int i = t; i < NC * NC; i += 256)
            Ml[(i >> 6) * 65 + (i & 63)] = Mb[i];
        if (t < NC) { Ksl[t] = Ksw[b * NC + t]; Vsl[t] = Vsw[b * NC + t]; }
    }
    __syncthreads();

    // pass 1: wave = pixel, lane = row c. A cached in registers.
    {
        const int px = w, c = lane;
        const float vxc = projl[px][128 + c];
        const float qc  = projl[px][c];
        const float uc  = fmaf(256.0f, vxc, Vsl[c]);
        float row[NC];
        float mx = -3.4e38f;
        #pragma unroll
        for (int d = 0; d < NC; ++d) {
            const float A = fmaf(uc, projl[px][64 + d],
                                 fmaf(vxc, Ksl[d], Ml[c * 65 + d])) * 0.125f;
            row[d] = A;
            mx = fmaxf(mx, A);
        }
        float sum = 0.f;
        #pragma unroll
        for (int d = 0; d < NC; ++d) sum += __expf(row[d] - mx);
        rsl[px][c] = qc / sum;
        mxl[px][c] = mx;
    }
    __syncthreads();

    // pass 2: wave = pixel, lane = col d
    {
        const int px = w, d = lane;
        const float kxd = projl[px][64 + d];
        const float Ksd = Ksl[d];
        float acc = 0.f;
        #pragma unroll 4
        for (int c = 0; c < NC; ++c) {
            const float vxc = projl[px][128 + c];
            const float uc = fmaf(256.0f, vxc, Vsl[c]);
            const float A = fmaf(uc, kxd, fmaf(vxc, Ksd, Ml[c * 65 + d])) * 0.125f;
            acc = fmaf(rsl[px][c], __expf(A - mxl[px][c]), acc);
        }
        outl[px][d] = acc;
    }
    __syncthreads();

    // out proj + residual + layernorm
    {
        const int col = t & 127;
        const int pxg = t >> 7;
        const int px0 = 2 * pxg, px1 = px0 + 1;
        float acc0 = 0.f, acc1 = 0.f;
        #pragma unroll 4
        for (int k = 0; k < NC; ++k) {
            const float wv = Wout[k * CC + col];
            acc0 = fmaf(outl[px0][k], wv, acc0);
            acc1 = fmaf(outl[px1][k], wv, acc1);
        }
        const float bb = bout[col];
        const float y0 = acc0 + bb + xl[px0][col];
        const float y1 = acc1 + bb + xl[px1][col];

        float s10 = y0, s20 = y0 * y0, s11 = y1, s21 = y1 * y1;
        #pragma unroll
        for (int off = 32; off >= 1; off >>= 1) {
            s10 += __shfl_down(s10, off);
            s20 += __shfl_down(s20, off);
            s11 += __shfl_down(s11, off);
            s21 += __shfl_down(s21, off);
        }
        const int half = (t >> 6) & 1;
        if (lane == 0) {
            redl[pxg][half][0] = s10; redl[pxg][half][1] = s20;
            redl[pxg][half][2] = s11; redl[pxg][half][3] = s21;
        }
        __syncthreads();
        const float S10 = redl[pxg][0][0] + redl[pxg][1][0];
        const float S20 = redl[pxg][0][1] + redl[pxg][1][1];
        const float S11 = redl[pxg][0][2] + redl[pxg][1][2];
        const float S21 = redl[pxg][0][3] + redl[pxg][1][3];
        const float mu0 = S10 * (1.f / 128.f);
        const float var0 = S20 * (1.f / 128.f) - mu0 * mu0;
        const float mu1 = S11 * (1.f / 128.f);
        const float var1 = S21 * (1.f / 128.f) - mu1 * mu1;
        const float r0 = rsqrtf(var0 + 1e-6f), r1 = rsqrtf(var1 + 1e-6f);
        const float gg = ln_scale[col], be = ln_bias[col];
        out[(size_t)(px0g + px0) * CC + col] = (y0 - mu0) * r0 * gg + be;
        out[(size_t)(px0g + px1) * CC + col] = (y1 - mu1) * r1 * gg + be;
    }
}

// ---------------------------------------------------------------------------
extern "C" void kernel_launch(void* const* d_in, const int* in_sizes, int n_in,
                              void* d_out, int out_size, void* d_ws, size_t ws_size,
                              hipStream_t stream) {
    const float* x        = (const float*)d_in[0];
    const float* s        = (const float*)d_in[1];
    const float* a        = (const float*)d_in[2];
    const float* Wq       = (const float*)d_in[3];
    const float* bq       = (const float*)d_in[4];
    const float* Wkx      = (const float*)d_in[5];
    const float* bkx      = (const float*)d_in[6];
    const float* Wvx      = (const float*)d_in[7];
    const float* bvx      = (const float*)d_in[8];
    const float* Wks      = (const float*)d_in[9];
    const float* bks      = (const float*)d_in[10];
    const float* Wvs      = (const float*)d_in[11];
    const float* bvs      = (const float*)d_in[12];
    const float* Wout     = (const float*)d_in[13];
    const float* bout     = (const float*)d_in[14];
    const float* ln_scale = (const float*)d_in[15];
    const float* ln_bias  = (const float*)d_in[16];

    float* ws  = (float*)d_ws;
    float* Mw  = ws;                 // 16384 floats
    float* Ksw = ws + 16384;         // 256
    float* Vsw = ws + 16640;         // 256
    float* Pw  = ws + 16896;         // 4096*192 = 786432

    // zero the atomic accumulators (Mw|Ksw|Vsw are contiguous: 16896 floats)
    hipMemsetAsync(Mw, 0, 16896 * sizeof(float), stream);

    proj_kernel<<<NTEXT + 512, 256, 0, stream>>>(
        x, Wq, bq, Wkx, bkx, Wvx, bvx, s, a, Wks, bks, Wvs, bvs,
        Pw, Mw, Ksw, Vsw);
    pixel_kernel<<<(BB * 1024) / PXB, 256, 0, stream>>>(
        x, Pw, Wout, bout, ln_scale, ln_bias, Mw, Ksw, Vsw, (float*)d_out);
}